// Round 5
// baseline (1936.764 us; speedup 1.0000x reference)
//
#include <hip/hip_runtime.h>
#include <hip/hip_bf16.h>

#define IN_DIM  128
#define OUT_DIM 64
#define SCAN_CHUNK 1024   // 256 threads x 4 elems
#define BSH 7             // 128 nodes per bucket
#define BNODES 128

// ---------------------------------------------------------------------------
// Prologue: degree histogram -> exclusive scan (node offsets + bucket cursors)
// ---------------------------------------------------------------------------
__global__ void k_zero(unsigned* __restrict__ p, int n) {
    int i = blockIdx.x * blockDim.x + threadIdx.x;
    if (i < n) p[i] = 0u;
}

__global__ void k_hist(const int* __restrict__ dst, unsigned* __restrict__ cnt, int nE) {
    int e = blockIdx.x * blockDim.x + threadIdx.x;
    if (e < nE) atomicAdd(&cnt[dst[e]], 1u);
}

__global__ __launch_bounds__(256) void k_scanA(const unsigned* __restrict__ cnt,
                                               unsigned* __restrict__ offs,
                                               unsigned* __restrict__ partials,
                                               float* __restrict__ dinv, int n) {
    __shared__ unsigned sums[256];
    int base = blockIdx.x * SCAN_CHUNK + threadIdx.x * 4;
    unsigned v[4]; unsigned s = 0;
#pragma unroll
    for (int k = 0; k < 4; ++k) {
        int i = base + k;
        unsigned c = (i < n) ? cnt[i] : 0u;
        if (i < n) dinv[i] = rsqrtf((float)c + 1.0f);
        v[k] = s; s += c;
    }
    sums[threadIdx.x] = s;
    __syncthreads();
    for (int d = 1; d < 256; d <<= 1) {
        unsigned t = (threadIdx.x >= (unsigned)d) ? sums[threadIdx.x - d] : 0u;
        __syncthreads();
        sums[threadIdx.x] += t;
        __syncthreads();
    }
    unsigned excl = sums[threadIdx.x] - s;
#pragma unroll
    for (int k = 0; k < 4; ++k) {
        int i = base + k;
        if (i < n) offs[i] = excl + v[k];
    }
    if (threadIdx.x == 255) partials[blockIdx.x] = sums[255];
}

__global__ void k_scanB(unsigned* __restrict__ partials, int nb) {
    __shared__ unsigned s[256];
    unsigned v = (threadIdx.x < (unsigned)nb) ? partials[threadIdx.x] : 0u;
    s[threadIdx.x] = v;
    __syncthreads();
    for (int d = 1; d < 256; d <<= 1) {
        unsigned t = (threadIdx.x >= (unsigned)d) ? s[threadIdx.x - d] : 0u;
        __syncthreads();
        s[threadIdx.x] += t;
        __syncthreads();
    }
    if (threadIdx.x < (unsigned)nb) partials[threadIdx.x] = s[threadIdx.x] - v;
}

// node offsets += block partial; every 128th node seeds its bucket cursor
__global__ void k_scanC(unsigned* __restrict__ offs, const unsigned* __restrict__ partials,
                        unsigned* __restrict__ bcurs, int n) {
    int i = blockIdx.x * blockDim.x + threadIdx.x;
    if (i < n) {
        unsigned o = offs[i] + partials[i / SCAN_CHUNK];
        offs[i] = o;
        if ((i & (BNODES - 1)) == 0) bcurs[i >> BSH] = o;
    }
}

// ---------------------------------------------------------------------------
// 8-rows-per-wave linear tile (W in LDS, one W read amortized over 8 rows)
// ---------------------------------------------------------------------------
template <int KD, bool RELU>
__device__ __forceinline__ void lin_tile(const float* __restrict__ in,
                                         const float* __restrict__ Wl,
                                         const float* __restrict__ dinv,
                                         float* __restrict__ outp,
                                         int n, int tile, int wid, int lane) {
    int r0 = (tile * 4 + wid) * 8;
    if (r0 >= n) return;
    const float4* base[8];
    float dv[8];
    int rows[8];
#pragma unroll
    for (int r = 0; r < 8; ++r) {
        int row = r0 + r; if (row > n - 1) row = n - 1;   // dup-tail benign
        rows[r] = row;
        base[r] = (const float4*)(in + (size_t)row * KD);
        dv[r] = dinv[row];
    }
    float acc[8] = {0.f, 0.f, 0.f, 0.f, 0.f, 0.f, 0.f, 0.f};
    for (int k4 = 0; k4 < KD / 4; ++k4) {
        float w0 = Wl[(4 * k4 + 0) * 64 + lane];
        float w1 = Wl[(4 * k4 + 1) * 64 + lane];
        float w2 = Wl[(4 * k4 + 2) * 64 + lane];
        float w3 = Wl[(4 * k4 + 3) * 64 + lane];
#pragma unroll
        for (int r = 0; r < 8; ++r) {
            float4 xv = base[r][k4];                 // wave-uniform broadcast
            float a = xv.x, b = xv.y, c = xv.z, d = xv.w;
            if (RELU) {
                a = fmaxf(dv[r] * a, 0.f); b = fmaxf(dv[r] * b, 0.f);
                c = fmaxf(dv[r] * c, 0.f); d = fmaxf(dv[r] * d, 0.f);
            }
            acc[r] += a * w0 + b * w1 + c * w2 + d * w3;
        }
    }
#pragma unroll
    for (int r = 0; r < 8; ++r)
        outp[(size_t)rows[r] * 64 + lane] = dv[r] * acc[r];
}

// ---------------------------------------------------------------------------
// Mega kernel: {layer-1 linear tiles} + {edge bucketing}, block-range split.
// Bucketing: rec = (dst&127)<<17 | src, appended at bucket cursor (sequential
// within bucket -> near-full write-line utilization vs full random scatter).
// ---------------------------------------------------------------------------
__global__ __launch_bounds__(256) void k_mega(const float* __restrict__ x,
                                              const float* __restrict__ W,
                                              const float* __restrict__ dinv,
                                              float* __restrict__ hs, int n,
                                              const int* __restrict__ src,
                                              const int* __restrict__ dst,
                                              unsigned* __restrict__ bcurs,
                                              unsigned* __restrict__ ebuf, int nE) {
    int nL = (n + 31) / 32;            // 32 rows per lin block
    int nS = (nE + 255) / 256;         // 256 edges per bucket-scatter block
    long tot = nL + nS;
    long b = blockIdx.x;
    int lo = (int)((b * nL) / tot);
    int hi = (int)(((b + 1) * nL) / tot);
    if (hi > lo) {
        __shared__ float Wl[IN_DIM * OUT_DIM];   // 32 KiB
        for (int i = threadIdx.x; i < IN_DIM * OUT_DIM; i += 256) Wl[i] = W[i];
        __syncthreads();
        lin_tile<IN_DIM, false>(x, Wl, dinv, hs, n, lo,
                                threadIdx.x >> 6, threadIdx.x & 63);
    } else {
        int sIdx = (int)(b - lo);
        int e = sIdx * 256 + threadIdx.x;
        if (e < nE) {
            int d = dst[e];
            unsigned rec = ((unsigned)(d & (BNODES - 1)) << 17) | (unsigned)src[e];
            unsigned p = atomicAdd(&bcurs[d >> BSH], 1u);
            ebuf[p] = rec;
        }
    }
}

// Standalone layer-2 linear (relu + dinv fused on input)
__global__ __launch_bounds__(256) void k_lin2(const float* __restrict__ agg1,
                                              const float* __restrict__ W,
                                              const float* __restrict__ dinv,
                                              float* __restrict__ hs2, int n) {
    __shared__ float Wl[OUT_DIM * OUT_DIM];  // 16 KiB
    for (int i = threadIdx.x; i < OUT_DIM * OUT_DIM; i += 256) Wl[i] = W[i];
    __syncthreads();
    lin_tile<OUT_DIM, true>(agg1, Wl, dinv, hs2, n, blockIdx.x,
                            threadIdx.x >> 6, threadIdx.x & 63);
}

// ---------------------------------------------------------------------------
// Bucket aggregate: one block per 128-node bucket, 128x64 f32 LDS accumulator.
// Wave-per-edge: broadcast rec, coalesced 256B gather of hs[src], LDS atomic
// add (lane-stride 4B = conflict-free 2-way). Self-loop + FIN dinv folded
// into the contiguous writeout.
// ---------------------------------------------------------------------------
template <bool FIN>
__global__ __launch_bounds__(256) void k_bagg(const float* __restrict__ hs,
                                              const unsigned* __restrict__ offs,
                                              const unsigned* __restrict__ ebuf,
                                              const float* __restrict__ dinv,
                                              float* __restrict__ outb,
                                              int n, int nE) {
    __shared__ __align__(16) float acc[BNODES * 64];   // 32 KiB
    int node0 = blockIdx.x << BSH;
    int nloc = min(BNODES, n - node0);
    float4* a4 = (float4*)acc;
    for (int i = threadIdx.x; i < BNODES * 16; i += 256)
        a4[i] = float4{0.f, 0.f, 0.f, 0.f};
    __syncthreads();
    int wid = threadIdx.x >> 6, lane = threadIdx.x & 63;
    unsigned ebeg = offs[node0];
    unsigned eend = (node0 + BNODES >= n) ? (unsigned)nE : offs[node0 + BNODES];
    for (unsigned e0 = ebeg + wid * 64; e0 < eend; e0 += 256) {
        unsigned c = min(64u, eend - e0);
        unsigned rec = (lane < (int)c) ? ebuf[e0 + lane] : 0u;   // coalesced
        unsigned k = 0;
        for (; k + 4 <= c; k += 4) {
            unsigned r0 = __shfl(rec, (int)k);
            unsigned r1 = __shfl(rec, (int)k + 1);
            unsigned r2 = __shfl(rec, (int)k + 2);
            unsigned r3 = __shfl(rec, (int)k + 3);
            float v0 = hs[(size_t)(r0 & 0x1FFFFu) * 64 + lane];
            float v1 = hs[(size_t)(r1 & 0x1FFFFu) * 64 + lane];
            float v2 = hs[(size_t)(r2 & 0x1FFFFu) * 64 + lane];
            float v3 = hs[(size_t)(r3 & 0x1FFFFu) * 64 + lane];
            atomicAdd(&acc[(r0 >> 17) * 64 + lane], v0);
            atomicAdd(&acc[(r1 >> 17) * 64 + lane], v1);
            atomicAdd(&acc[(r2 >> 17) * 64 + lane], v2);
            atomicAdd(&acc[(r3 >> 17) * 64 + lane], v3);
        }
        for (; k < c; ++k) {
            unsigned r = __shfl(rec, (int)k);
            atomicAdd(&acc[(r >> 17) * 64 + lane],
                      hs[(size_t)(r & 0x1FFFFu) * 64 + lane]);
        }
    }
    __syncthreads();
    for (int l = wid; l < nloc; l += 4) {
        int node = node0 + l;
        float v = acc[l * 64 + lane] + hs[(size_t)node * 64 + lane];  // self-loop
        if (FIN) v *= dinv[node];
        outb[(size_t)node * 64 + lane] = v;
    }
}

// ---------------------------------------------------------------------------
extern "C" void kernel_launch(void* const* d_in, const int* in_sizes, int n_in,
                              void* d_out, int out_size, void* d_ws, size_t ws_size,
                              hipStream_t stream) {
    const float* x  = (const float*)d_in[0];
    const int*   ei = (const int*)d_in[1];
    const float* W1 = (const float*)d_in[2];
    const float* W2 = (const float*)d_in[3];
    float* out = (float*)d_out;

    int n  = in_sizes[0] / IN_DIM;   // 100000
    int nE = in_sizes[1] / 2;        // 1600000
    const int* src = ei;
    const int* dst = ei + nE;
    int NB = (n + BNODES - 1) / BNODES;   // 782 buckets

    char* w = (char*)d_ws;
    size_t nAl = ((size_t)n * 4 + 255) & ~(size_t)255;
    float*    dinv     = (float*)w;                 w += nAl;
    unsigned* cnt      = (unsigned*)w;              w += nAl;
    unsigned* offs     = (unsigned*)w;              w += nAl;
    unsigned* bcurs    = (unsigned*)w;              w += ((size_t)NB * 4 + 255) & ~(size_t)255;
    unsigned* partials = (unsigned*)w;              w += 4096;
    unsigned* ebuf     = (unsigned*)w;              w += ((size_t)nE * 4 + 255) & ~(size_t)255;
    float*    hs       = (float*)w;                 w += (size_t)n * 64 * 4;
    float*    agg      = (float*)w;

    int nb = (n + SCAN_CHUNK - 1) / SCAN_CHUNK;
    int gE = (nE + 255) / 256;
    int gN = (n + 255) / 256;
    int nL = (n + 31) / 32;
    int nS = (nE + 255) / 256;

    // --- prologue: degrees, offsets, bucket cursors ---
    k_zero<<<gN, 256, 0, stream>>>(cnt, n);
    k_hist<<<gE, 256, 0, stream>>>(dst, cnt, nE);
    k_scanA<<<nb, 256, 0, stream>>>(cnt, offs, partials, dinv, n);
    k_scanB<<<1, 256, 0, stream>>>(partials, nb);
    k_scanC<<<gN, 256, 0, stream>>>(offs, partials, bcurs, n);

    // --- fused: layer-1 linear + edge bucketing ---
    k_mega<<<nL + nS, 256, 0, stream>>>(x, W1, dinv, hs, n, src, dst, bcurs, ebuf, nE);

    // --- layer 1 aggregate (LDS-bucketed) ---
    k_bagg<false><<<NB, 256, 0, stream>>>(hs, offs, ebuf, dinv, agg, n, nE);

    // --- layer 2 ---
    k_lin2<<<nL, 256, 0, stream>>>(agg, W2, dinv, hs, n);
    k_bagg<true><<<NB, 256, 0, stream>>>(hs, offs, ebuf, dinv, out, n, nE);
}

// Round 6
// 418.966 us; speedup vs baseline: 4.6227x; 4.6227x over previous
//
#include <hip/hip_runtime.h>
#include <hip/hip_bf16.h>

#define IN_DIM  128
#define OUT_DIM 64
#define SCAN_CHUNK 1024   // 256 threads x 4 elems

// ---------------------------------------------------------------------------
// Prologue: degree histogram (also records per-edge rank) -> exclusive scan
// ---------------------------------------------------------------------------
__global__ void k_zero(unsigned* __restrict__ p, int n) {
    int i = blockIdx.x * blockDim.x + threadIdx.x;
    if (i < n) p[i] = 0u;
}

// rank[e] = number of earlier edges with same dst (atomic order; any perm ok)
__global__ void k_hist2(const int* __restrict__ dst, unsigned* __restrict__ cnt,
                        unsigned short* __restrict__ rank, int nE) {
    int e = blockIdx.x * blockDim.x + threadIdx.x;
    if (e < nE) {
        unsigned k = atomicAdd(&cnt[dst[e]], 1u);
        rank[e] = (unsigned short)k;       // sequential write
    }
}

__global__ __launch_bounds__(256) void k_scanA(const unsigned* __restrict__ cnt,
                                               unsigned* __restrict__ offs,
                                               unsigned* __restrict__ partials,
                                               float* __restrict__ dinv, int n) {
    __shared__ unsigned sums[256];
    int base = blockIdx.x * SCAN_CHUNK + threadIdx.x * 4;
    unsigned v[4]; unsigned s = 0;
#pragma unroll
    for (int k = 0; k < 4; ++k) {
        int i = base + k;
        unsigned c = (i < n) ? cnt[i] : 0u;
        if (i < n) dinv[i] = rsqrtf((float)c + 1.0f);   // +1 self-loop
        v[k] = s; s += c;
    }
    sums[threadIdx.x] = s;
    __syncthreads();
    for (int d = 1; d < 256; d <<= 1) {
        unsigned t = (threadIdx.x >= (unsigned)d) ? sums[threadIdx.x - d] : 0u;
        __syncthreads();
        sums[threadIdx.x] += t;
        __syncthreads();
    }
    unsigned excl = sums[threadIdx.x] - s;
#pragma unroll
    for (int k = 0; k < 4; ++k) {
        int i = base + k;
        if (i < n) offs[i] = excl + v[k];
    }
    if (threadIdx.x == 255) partials[blockIdx.x] = sums[255];
}

__global__ void k_scanB(unsigned* __restrict__ partials, int nb) {
    __shared__ unsigned s[256];
    unsigned v = (threadIdx.x < (unsigned)nb) ? partials[threadIdx.x] : 0u;
    s[threadIdx.x] = v;
    __syncthreads();
    for (int d = 1; d < 256; d <<= 1) {
        unsigned t = (threadIdx.x >= (unsigned)d) ? s[threadIdx.x - d] : 0u;
        __syncthreads();
        s[threadIdx.x] += t;
        __syncthreads();
    }
    if (threadIdx.x < (unsigned)nb) partials[threadIdx.x] = s[threadIdx.x] - v;
}

__global__ void k_scanC(unsigned* __restrict__ offs, const unsigned* __restrict__ partials,
                        int n) {
    int i = blockIdx.x * blockDim.x + threadIdx.x;
    if (i < n) offs[i] += partials[i / SCAN_CHUNK];
}

// ---------------------------------------------------------------------------
// Atomic-free edge scatter: perm[offs[dst] + rank] = src (non-temporal store
// avoids cross-XCD L2 write-allocate churn on the random 4B writes)
// ---------------------------------------------------------------------------
__global__ void k_scat(const int* __restrict__ src, const int* __restrict__ dst,
                       const unsigned short* __restrict__ rank,
                       const unsigned* __restrict__ offs,
                       int* __restrict__ perm, int nE) {
    int e = blockIdx.x * blockDim.x + threadIdx.x;
    if (e < nE) {
        unsigned p = offs[dst[e]] + (unsigned)rank[e];
        __builtin_nontemporal_store(src[e], &perm[p]);
    }
}

// ---------------------------------------------------------------------------
// 8-rows-per-wave linear tile (W in LDS, one W read amortized over 8 rows)
// ---------------------------------------------------------------------------
template <int KD, bool RELU>
__device__ __forceinline__ void lin_tile(const float* __restrict__ in,
                                         const float* __restrict__ Wl,
                                         const float* __restrict__ dinv,
                                         float* __restrict__ outp,
                                         int n, int tile, int wid, int lane) {
    int r0 = (tile * 4 + wid) * 8;
    if (r0 >= n) return;
    const float4* base[8];
    float dv[8];
    int rows[8];
#pragma unroll
    for (int r = 0; r < 8; ++r) {
        int row = r0 + r; if (row > n - 1) row = n - 1;   // dup-tail benign
        rows[r] = row;
        base[r] = (const float4*)(in + (size_t)row * KD);
        dv[r] = dinv[row];
    }
    float acc[8] = {0.f, 0.f, 0.f, 0.f, 0.f, 0.f, 0.f, 0.f};
    for (int k4 = 0; k4 < KD / 4; ++k4) {
        float w0 = Wl[(4 * k4 + 0) * 64 + lane];
        float w1 = Wl[(4 * k4 + 1) * 64 + lane];
        float w2 = Wl[(4 * k4 + 2) * 64 + lane];
        float w3 = Wl[(4 * k4 + 3) * 64 + lane];
#pragma unroll
        for (int r = 0; r < 8; ++r) {
            float4 xv = base[r][k4];                 // wave-uniform broadcast
            float a = xv.x, b = xv.y, c = xv.z, d = xv.w;
            if (RELU) {
                a = fmaxf(dv[r] * a, 0.f); b = fmaxf(dv[r] * b, 0.f);
                c = fmaxf(dv[r] * c, 0.f); d = fmaxf(dv[r] * d, 0.f);
            }
            acc[r] += a * w0 + b * w1 + c * w2 + d * w3;
        }
    }
#pragma unroll
    for (int r = 0; r < 8; ++r)
        outp[(size_t)rows[r] * 64 + lane] = dv[r] * acc[r];
}

__global__ __launch_bounds__(256) void k_lin1(const float* __restrict__ x,
                                              const float* __restrict__ W,
                                              const float* __restrict__ dinv,
                                              float* __restrict__ hs, int n) {
    __shared__ float Wl[IN_DIM * OUT_DIM];   // 32 KiB
    for (int i = threadIdx.x; i < IN_DIM * OUT_DIM; i += 256) Wl[i] = W[i];
    __syncthreads();
    lin_tile<IN_DIM, false>(x, Wl, dinv, hs, n, blockIdx.x,
                            threadIdx.x >> 6, threadIdx.x & 63);
}

__global__ __launch_bounds__(256) void k_lin2(const float* __restrict__ agg1,
                                              const float* __restrict__ W,
                                              const float* __restrict__ dinv,
                                              float* __restrict__ hs2, int n) {
    __shared__ float Wl[OUT_DIM * OUT_DIM];  // 16 KiB
    for (int i = threadIdx.x; i < OUT_DIM * OUT_DIM; i += 256) Wl[i] = W[i];
    __syncthreads();
    lin_tile<OUT_DIM, true>(agg1, Wl, dinv, hs2, n, blockIdx.x,
                            threadIdx.x >> 6, threadIdx.x & 63);
}

// ---------------------------------------------------------------------------
// CSR gather, 8-way ILP: one wave per node, lane = feature dim.
// acc = hs[r] (self-loop) + sum over neighbors; FIN applies final dinv[r].
// ---------------------------------------------------------------------------
template <bool FIN>
__global__ __launch_bounds__(256) void k_gather(const float* __restrict__ hs,
                                                const unsigned* __restrict__ offs,
                                                const int* __restrict__ perm,
                                                const float* __restrict__ dinv,
                                                float* __restrict__ outb,
                                                int n, int nE) {
    int lane = threadIdx.x & 63;
    int r = blockIdx.x * 4 + (threadIdx.x >> 6);
    if (r >= n) return;
    unsigned beg = offs[r];
    unsigned end = (r + 1 < n) ? offs[r + 1] : (unsigned)nE;
    float a0 = hs[(size_t)r * 64 + lane];            // self-loop term
    float a1 = 0.f, a2 = 0.f, a3 = 0.f, a4 = 0.f, a5 = 0.f, a6 = 0.f, a7 = 0.f;
    for (unsigned e0 = beg; e0 < end; e0 += 64) {
        unsigned c = min(64u, end - e0);
        int sl = (lane < (int)c) ? perm[e0 + lane] : 0;   // coalesced edge read
        unsigned k = 0;
        for (; k + 8 <= c; k += 8) {
            int s0 = __shfl(sl, (int)k);
            int s1 = __shfl(sl, (int)k + 1);
            int s2 = __shfl(sl, (int)k + 2);
            int s3 = __shfl(sl, (int)k + 3);
            int s4 = __shfl(sl, (int)k + 4);
            int s5 = __shfl(sl, (int)k + 5);
            int s6 = __shfl(sl, (int)k + 6);
            int s7 = __shfl(sl, (int)k + 7);
            float v0 = hs[(size_t)s0 * 64 + lane];
            float v1 = hs[(size_t)s1 * 64 + lane];
            float v2 = hs[(size_t)s2 * 64 + lane];
            float v3 = hs[(size_t)s3 * 64 + lane];
            float v4 = hs[(size_t)s4 * 64 + lane];
            float v5 = hs[(size_t)s5 * 64 + lane];
            float v6 = hs[(size_t)s6 * 64 + lane];
            float v7 = hs[(size_t)s7 * 64 + lane];
            a0 += v0; a1 += v1; a2 += v2; a3 += v3;
            a4 += v4; a5 += v5; a6 += v6; a7 += v7;
        }
        for (; k + 4 <= c; k += 4) {
            int s0 = __shfl(sl, (int)k);
            int s1 = __shfl(sl, (int)k + 1);
            int s2 = __shfl(sl, (int)k + 2);
            int s3 = __shfl(sl, (int)k + 3);
            float v0 = hs[(size_t)s0 * 64 + lane];
            float v1 = hs[(size_t)s1 * 64 + lane];
            float v2 = hs[(size_t)s2 * 64 + lane];
            float v3 = hs[(size_t)s3 * 64 + lane];
            a0 += v0; a1 += v1; a2 += v2; a3 += v3;
        }
        for (; k < c; ++k) {
            int s = __shfl(sl, (int)k);
            a0 += hs[(size_t)s * 64 + lane];
        }
    }
    float acc = ((a0 + a1) + (a2 + a3)) + ((a4 + a5) + (a6 + a7));
    if (FIN) acc *= dinv[r];
    outb[(size_t)r * 64 + lane] = acc;
}

// ---------------------------------------------------------------------------
extern "C" void kernel_launch(void* const* d_in, const int* in_sizes, int n_in,
                              void* d_out, int out_size, void* d_ws, size_t ws_size,
                              hipStream_t stream) {
    const float* x  = (const float*)d_in[0];
    const int*   ei = (const int*)d_in[1];
    const float* W1 = (const float*)d_in[2];
    const float* W2 = (const float*)d_in[3];
    float* out = (float*)d_out;

    int n  = in_sizes[0] / IN_DIM;   // 100000
    int nE = in_sizes[1] / 2;        // 1600000
    const int* src = ei;
    const int* dst = ei + nE;

    // workspace carve-up (256B-aligned); d_out doubles as the layer-1 agg buffer
    char* w = (char*)d_ws;
    size_t nAl = ((size_t)n * 4 + 255) & ~(size_t)255;
    float*          dinv     = (float*)w;          w += nAl;
    unsigned*       cnt      = (unsigned*)w;       w += nAl;
    unsigned*       offs     = (unsigned*)w;       w += nAl;
    unsigned*       partials = (unsigned*)w;       w += 4096;
    unsigned short* rank     = (unsigned short*)w; w += ((size_t)nE * 2 + 255) & ~(size_t)255;
    int*            perm     = (int*)w;            w += ((size_t)nE * 4 + 255) & ~(size_t)255;
    float*          hs       = (float*)w;          w += (size_t)n * 64 * 4;
    float*          agg      = out;                // layer-1 aggregate lives in d_out

    int nb   = (n + SCAN_CHUNK - 1) / SCAN_CHUNK;
    int gE   = (nE + 255) / 256;
    int gN   = (n + 255) / 256;
    int gRow = (n + 3) / 4;
    int nL   = (n + 31) / 32;

    // --- prologue: degrees + per-edge ranks, node offsets ---
    k_zero<<<gN, 256, 0, stream>>>(cnt, n);
    k_hist2<<<gE, 256, 0, stream>>>(dst, cnt, rank, nE);
    k_scanA<<<nb, 256, 0, stream>>>(cnt, offs, partials, dinv, n);
    k_scanB<<<1, 256, 0, stream>>>(partials, nb);
    k_scanC<<<gN, 256, 0, stream>>>(offs, partials, n);

    // --- layer 1 ---
    k_lin1<<<nL, 256, 0, stream>>>(x, W1, dinv, hs, n);
    k_scat<<<gE, 256, 0, stream>>>(src, dst, rank, offs, perm, nE);
    k_gather<false><<<gRow, 256, 0, stream>>>(hs, offs, perm, dinv, agg, n, nE);

    // --- layer 2 (reuse hs for hs2; final dinv folded into gather) ---
    k_lin2<<<nL, 256, 0, stream>>>(agg, W2, dinv, hs, n);
    k_gather<true><<<gRow, 256, 0, stream>>>(hs, offs, perm, dinv, out, n, nE);
}

// Round 7
// 332.307 us; speedup vs baseline: 5.8282x; 1.2608x over previous
//
#include <hip/hip_runtime.h>
#include <hip/hip_bf16.h>

#define IN_DIM  128
#define OUT_DIM 64
#define SCAN_CHUNK 1024   // 256 threads x 4 elems

// ---------------------------------------------------------------------------
// Prologue: degree histogram (also records per-edge rank) -> exclusive scan
// ---------------------------------------------------------------------------
__global__ void k_zero(unsigned* __restrict__ p, int n) {
    int i = blockIdx.x * blockDim.x + threadIdx.x;
    if (i < n) p[i] = 0u;
}

// rank[e] = number of earlier edges with same dst (atomic order; any perm ok)
__global__ void k_hist2(const int* __restrict__ dst, unsigned* __restrict__ cnt,
                        unsigned short* __restrict__ rank, int nE) {
    int e = blockIdx.x * blockDim.x + threadIdx.x;
    if (e < nE) {
        unsigned k = atomicAdd(&cnt[dst[e]], 1u);
        rank[e] = (unsigned short)k;       // sequential write
    }
}

__global__ __launch_bounds__(256) void k_scanA(const unsigned* __restrict__ cnt,
                                               unsigned* __restrict__ offs,
                                               unsigned* __restrict__ partials,
                                               float* __restrict__ dinv, int n) {
    __shared__ unsigned sums[256];
    int base = blockIdx.x * SCAN_CHUNK + threadIdx.x * 4;
    unsigned v[4]; unsigned s = 0;
#pragma unroll
    for (int k = 0; k < 4; ++k) {
        int i = base + k;
        unsigned c = (i < n) ? cnt[i] : 0u;
        if (i < n) dinv[i] = rsqrtf((float)c + 1.0f);   // +1 self-loop
        v[k] = s; s += c;
    }
    sums[threadIdx.x] = s;
    __syncthreads();
    for (int d = 1; d < 256; d <<= 1) {
        unsigned t = (threadIdx.x >= (unsigned)d) ? sums[threadIdx.x - d] : 0u;
        __syncthreads();
        sums[threadIdx.x] += t;
        __syncthreads();
    }
    unsigned excl = sums[threadIdx.x] - s;
#pragma unroll
    for (int k = 0; k < 4; ++k) {
        int i = base + k;
        if (i < n) offs[i] = excl + v[k];
    }
    if (threadIdx.x == 255) partials[blockIdx.x] = sums[255];
}

__global__ void k_scanB(unsigned* __restrict__ partials, int nb) {
    __shared__ unsigned s[256];
    unsigned v = (threadIdx.x < (unsigned)nb) ? partials[threadIdx.x] : 0u;
    s[threadIdx.x] = v;
    __syncthreads();
    for (int d = 1; d < 256; d <<= 1) {
        unsigned t = (threadIdx.x >= (unsigned)d) ? s[threadIdx.x - d] : 0u;
        __syncthreads();
        s[threadIdx.x] += t;
        __syncthreads();
    }
    if (threadIdx.x < (unsigned)nb) partials[threadIdx.x] = s[threadIdx.x] - v;
}

__global__ void k_scanC(unsigned* __restrict__ offs, const unsigned* __restrict__ partials,
                        int n) {
    int i = blockIdx.x * blockDim.x + threadIdx.x;
    if (i < n) offs[i] += partials[i / SCAN_CHUNK];
}

// ---------------------------------------------------------------------------
// Atomic-free edge scatter: perm[offs[dst] + rank] = src (non-temporal store)
// ---------------------------------------------------------------------------
__global__ void k_scat(const int* __restrict__ src, const int* __restrict__ dst,
                       const unsigned short* __restrict__ rank,
                       const unsigned* __restrict__ offs,
                       int* __restrict__ perm, int nE) {
    int e = blockIdx.x * blockDim.x + threadIdx.x;
    if (e < nE) {
        unsigned p = offs[dst[e]] + (unsigned)rank[e];
        __builtin_nontemporal_store(src[e], &perm[p]);
    }
}

// ---------------------------------------------------------------------------
// Linear layer, LDS-staged: 32-row tile loaded COALESCED into LDS, then the
// per-row broadcast reads hit LDS (1-cycle-class broadcast) instead of global
// (600-900 cy latency). W in LDS [k][64], conflict-free (lane stride 1).
// RELU: relu(dinv*in) folded into the staging store (layer-2 input).
// Output: out[row][lane] = dinv[row] * (f(in[row]) @ W)[lane].
// ---------------------------------------------------------------------------
template <int KD, bool RELU>
__global__ __launch_bounds__(256) void k_lin(const float* __restrict__ in,
                                             const float* __restrict__ W,
                                             const float* __restrict__ dinv,
                                             float* __restrict__ outp, int n) {
    __shared__ float Wl[KD * 64];        // 32 KiB (KD=128) / 16 KiB (KD=64)
    __shared__ float xs[32 * KD];        // 16 KiB / 8 KiB
    for (int i = threadIdx.x; i < KD * 16; i += 256)
        ((float4*)Wl)[i] = ((const float4*)W)[i];

    int r0t = blockIdx.x * 32;
    const int F4 = 32 * KD / 4;          // float4s per x-tile
    const float4* gin = (const float4*)(in + (size_t)r0t * KD);
    for (int f = threadIdx.x; f < F4; f += 256) {
        int row = r0t + f / (KD / 4);
        float4 v = {0.f, 0.f, 0.f, 0.f};
        if (row < n) {
            v = gin[f];                  // coalesced: lanes -> consecutive 16B
            if (RELU) {
                float dv = dinv[row];
                v.x = fmaxf(dv * v.x, 0.f); v.y = fmaxf(dv * v.y, 0.f);
                v.z = fmaxf(dv * v.z, 0.f); v.w = fmaxf(dv * v.w, 0.f);
            }
        }
        ((float4*)xs)[f] = v;
    }
    __syncthreads();

    int wid = threadIdx.x >> 6, lane = threadIdx.x & 63;
    int r0 = wid * 8;                    // 8 rows per wave
    float acc[8] = {0.f, 0.f, 0.f, 0.f, 0.f, 0.f, 0.f, 0.f};
#pragma unroll 4
    for (int k4 = 0; k4 < KD / 4; ++k4) {
        float w0 = Wl[(4 * k4 + 0) * 64 + lane];
        float w1 = Wl[(4 * k4 + 1) * 64 + lane];
        float w2 = Wl[(4 * k4 + 2) * 64 + lane];
        float w3 = Wl[(4 * k4 + 3) * 64 + lane];
#pragma unroll
        for (int r = 0; r < 8; ++r) {
            float4 xv = *(const float4*)&xs[(r0 + r) * KD + 4 * k4];  // LDS broadcast
            acc[r] += xv.x * w0 + xv.y * w1 + xv.z * w2 + xv.w * w3;
        }
    }
#pragma unroll
    for (int r = 0; r < 8; ++r) {
        int row = r0t + r0 + r;
        if (row < n) outp[(size_t)row * 64 + lane] = dinv[row] * acc[r];
    }
}

// ---------------------------------------------------------------------------
// CSR gather, 8-way ILP: one wave per node, lane = feature dim.
// acc = hs[r] (self-loop) + sum over neighbors; FIN applies final dinv[r].
// ---------------------------------------------------------------------------
template <bool FIN>
__global__ __launch_bounds__(256) void k_gather(const float* __restrict__ hs,
                                                const unsigned* __restrict__ offs,
                                                const int* __restrict__ perm,
                                                const float* __restrict__ dinv,
                                                float* __restrict__ outb,
                                                int n, int nE) {
    int lane = threadIdx.x & 63;
    int r = blockIdx.x * 4 + (threadIdx.x >> 6);
    if (r >= n) return;
    unsigned beg = offs[r];
    unsigned end = (r + 1 < n) ? offs[r + 1] : (unsigned)nE;
    float a0 = hs[(size_t)r * 64 + lane];            // self-loop term
    float a1 = 0.f, a2 = 0.f, a3 = 0.f, a4 = 0.f, a5 = 0.f, a6 = 0.f, a7 = 0.f;
    for (unsigned e0 = beg; e0 < end; e0 += 64) {
        unsigned c = min(64u, end - e0);
        int sl = (lane < (int)c) ? perm[e0 + lane] : 0;   // coalesced edge read
        unsigned k = 0;
        for (; k + 8 <= c; k += 8) {
            int s0 = __shfl(sl, (int)k);
            int s1 = __shfl(sl, (int)k + 1);
            int s2 = __shfl(sl, (int)k + 2);
            int s3 = __shfl(sl, (int)k + 3);
            int s4 = __shfl(sl, (int)k + 4);
            int s5 = __shfl(sl, (int)k + 5);
            int s6 = __shfl(sl, (int)k + 6);
            int s7 = __shfl(sl, (int)k + 7);
            float v0 = hs[(size_t)s0 * 64 + lane];
            float v1 = hs[(size_t)s1 * 64 + lane];
            float v2 = hs[(size_t)s2 * 64 + lane];
            float v3 = hs[(size_t)s3 * 64 + lane];
            float v4 = hs[(size_t)s4 * 64 + lane];
            float v5 = hs[(size_t)s5 * 64 + lane];
            float v6 = hs[(size_t)s6 * 64 + lane];
            float v7 = hs[(size_t)s7 * 64 + lane];
            a0 += v0; a1 += v1; a2 += v2; a3 += v3;
            a4 += v4; a5 += v5; a6 += v6; a7 += v7;
        }
        for (; k + 4 <= c; k += 4) {
            int s0 = __shfl(sl, (int)k);
            int s1 = __shfl(sl, (int)k + 1);
            int s2 = __shfl(sl, (int)k + 2);
            int s3 = __shfl(sl, (int)k + 3);
            float v0 = hs[(size_t)s0 * 64 + lane];
            float v1 = hs[(size_t)s1 * 64 + lane];
            float v2 = hs[(size_t)s2 * 64 + lane];
            float v3 = hs[(size_t)s3 * 64 + lane];
            a0 += v0; a1 += v1; a2 += v2; a3 += v3;
        }
        for (; k < c; ++k) {
            int s = __shfl(sl, (int)k);
            a0 += hs[(size_t)s * 64 + lane];
        }
    }
    float acc = ((a0 + a1) + (a2 + a3)) + ((a4 + a5) + (a6 + a7));
    if (FIN) acc *= dinv[r];
    outb[(size_t)r * 64 + lane] = acc;
}

// ---------------------------------------------------------------------------
extern "C" void kernel_launch(void* const* d_in, const int* in_sizes, int n_in,
                              void* d_out, int out_size, void* d_ws, size_t ws_size,
                              hipStream_t stream) {
    const float* x  = (const float*)d_in[0];
    const int*   ei = (const int*)d_in[1];
    const float* W1 = (const float*)d_in[2];
    const float* W2 = (const float*)d_in[3];
    float* out = (float*)d_out;

    int n  = in_sizes[0] / IN_DIM;   // 100000
    int nE = in_sizes[1] / 2;        // 1600000
    const int* src = ei;
    const int* dst = ei + nE;

    // workspace carve-up (256B-aligned); d_out doubles as the layer-1 agg buffer
    char* w = (char*)d_ws;
    size_t nAl = ((size_t)n * 4 + 255) & ~(size_t)255;
    float*          dinv     = (float*)w;          w += nAl;
    unsigned*       cnt      = (unsigned*)w;       w += nAl;
    unsigned*       offs     = (unsigned*)w;       w += nAl;
    unsigned*       partials = (unsigned*)w;       w += 4096;
    unsigned short* rank     = (unsigned short*)w; w += ((size_t)nE * 2 + 255) & ~(size_t)255;
    int*            perm     = (int*)w;            w += ((size_t)nE * 4 + 255) & ~(size_t)255;
    float*          hs       = (float*)w;          w += (size_t)n * 64 * 4;
    float*          agg      = out;                // layer-1 aggregate lives in d_out

    int nb    = (n + SCAN_CHUNK - 1) / SCAN_CHUNK;
    int gE    = (nE + 255) / 256;
    int gN    = (n + 255) / 256;
    int gRow  = (n + 3) / 4;
    int gTile = (n + 31) / 32;

    // --- prologue: degrees + per-edge ranks, node offsets ---
    k_zero<<<gN, 256, 0, stream>>>(cnt, n);
    k_hist2<<<gE, 256, 0, stream>>>(dst, cnt, rank, nE);
    k_scanA<<<nb, 256, 0, stream>>>(cnt, offs, partials, dinv, n);
    k_scanB<<<1, 256, 0, stream>>>(partials, nb);
    k_scanC<<<gN, 256, 0, stream>>>(offs, partials, n);

    // --- layer 1 ---
    k_lin<IN_DIM, false><<<gTile, 256, 0, stream>>>(x, W1, dinv, hs, n);
    k_scat<<<gE, 256, 0, stream>>>(src, dst, rank, offs, perm, nE);
    k_gather<false><<<gRow, 256, 0, stream>>>(hs, offs, perm, dinv, agg, n, nE);

    // --- layer 2 (reuse hs for hs2; final dinv folded into gather) ---
    k_lin<OUT_DIM, true><<<gTile, 256, 0, stream>>>(agg, W2, dinv, hs, n);
    k_gather<true><<<gRow, 256, 0, stream>>>(hs, offs, perm, dinv, out, n, nE);
}